// Round 7
// baseline (267.742 us; speedup 1.0000x reference)
//
#include <hip/hip_runtime.h>
#include <math.h>

typedef float    floatx4 __attribute__((ext_vector_type(4)));
typedef _Float16 half8   __attribute__((ext_vector_type(8)));
typedef _Float16 half4v  __attribute__((ext_vector_type(4)));

constexpr int B    = 2;
constexpr int S    = 2048;
constexpr int NH   = 16;
constexpr int HD   = 64;
constexpr int DIM  = 1024;
constexpr int INNER = 1024;
constexpr int QKVN = 3072;
constexpr int NTOK = 4096;
constexpr float EPS = 1e-5f;
constexpr float MAX_SCALE = 10.0f;
constexpr float SCALE_LOG2E = 0.125f * 1.4426950408889634f;

#define MFMA16(a, b, c) __builtin_amdgcn_mfma_f32_16x16x16f16((a), (b), (c), 0, 0, 0)
// async global->LDS, 16B per lane; LDS dest = wave-uniform base + lane*16
#define GLD16(gp, lp) __builtin_amdgcn_global_load_lds( \
    (const __attribute__((address_space(1))) void*)(gp), \
    (__attribute__((address_space(3))) void*)(lp), 16, 0, 0)

// ---------------------------------------------------------------------------
// fp32 -> fp16 elementwise convert (8 elems/thread)
// ---------------------------------------------------------------------------
__global__ __launch_bounds__(256)
void cvt_f16(const float* __restrict__ in, _Float16* __restrict__ out, int n8) {
  int id = blockIdx.x * 256 + threadIdx.x;
  if (id >= n8) return;
  const float4 a = ((const float4*)in)[id * 2];
  const float4 b = ((const float4*)in)[id * 2 + 1];
  half8 o;
  o[0] = (_Float16)a.x; o[1] = (_Float16)a.y; o[2] = (_Float16)a.z; o[3] = (_Float16)a.w;
  o[4] = (_Float16)b.x; o[5] = (_Float16)b.y; o[6] = (_Float16)b.z; o[7] = (_Float16)b.w;
  ((half8*)out)[id] = o;
}

// ---------------------------------------------------------------------------
// w [K][N] fp32  ->  wT [N][K] fp16   (64x64 tiles through LDS)
// ---------------------------------------------------------------------------
__global__ __launch_bounds__(256)
void transpose_w(const float* __restrict__ w, _Float16* __restrict__ wT, int K, int N) {
  __shared__ _Float16 T[64 * 72];
  const int k0 = blockIdx.y * 64, n0 = blockIdx.x * 64;
  const int tid = threadIdx.x;
#pragma unroll
  for (int i = 0; i < 4; ++i) {
    int id = tid + 256 * i;
    int r = id >> 4, c = id & 15;
    float4 v = *(const float4*)&w[(size_t)(k0 + r) * N + n0 + c * 4];
    half4v s; s[0] = (_Float16)v.x; s[1] = (_Float16)v.y;
    s[2] = (_Float16)v.z; s[3] = (_Float16)v.w;
    *(half4v*)&T[r * 72 + c * 4] = s;
  }
  __syncthreads();
#pragma unroll
  for (int i = 0; i < 2; ++i) {
    int id = tid + 256 * i;
    int n = id >> 3, cs = id & 7;
    half8 o;
#pragma unroll
    for (int jj = 0; jj < 8; ++jj) o[jj] = T[(cs * 8 + jj) * 72 + n];
    *(half8*)&wT[(size_t)(n0 + n) * K + k0 + cs * 8] = o;
  }
}

// ---------------------------------------------------------------------------
// fp16 MFMA GEMM, m97 structure: C[M][N] = A[M][K] @ BT[N][K]^T + bias
// 128x128 tile, 256 thr, BK=32, staging via global_load_lds width=16 into
// UNPADDED [128][32] LDS tiles (async DMA requires contiguous lane order).
// ---------------------------------------------------------------------------
template<bool OUT_F16, typename OutT>
__global__ __launch_bounds__(256)
void gemm_bt(const _Float16* __restrict__ A, const _Float16* __restrict__ BT,
             const float* __restrict__ bias, OutT* __restrict__ C, int N, int K) {
  __shared__ _Float16 As[128 * 32];
  __shared__ _Float16 Bs[128 * 32];
  const int tid = threadIdx.x;
  const int wave = tid >> 6, lane = tid & 63, quad = lane >> 4, l16 = lane & 15;
  const int wm = wave >> 1, wn = wave & 1;
  const int m0 = blockIdx.y * 128, n0 = blockIdx.x * 128;

  // two 16B issues per matrix per K-step cover 128 rows x 32 halves
  const int i0 = tid, i1 = tid + 256;
  const int r0 = i0 >> 2, c0 = (i0 & 3) * 8;
  const int r1 = i1 >> 2, c1 = (i1 & 3) * 8;
  const _Float16* A0 = A + (size_t)(m0 + r0) * K + c0;
  const _Float16* A1 = A + (size_t)(m0 + r1) * K + c1;
  const _Float16* B0 = BT + (size_t)(n0 + r0) * K + c0;
  const _Float16* B1 = BT + (size_t)(n0 + r1) * K + c1;

  floatx4 acc[4][4] = {};

  for (int k0 = 0; k0 < K; k0 += 32) {
    __syncthreads();
    GLD16(A0 + k0, &As[i0 * 8]);
    GLD16(A1 + k0, &As[i1 * 8]);
    GLD16(B0 + k0, &Bs[i0 * 8]);
    GLD16(B1 + k0, &Bs[i1 * 8]);
    __syncthreads();
    half8 a[4], b[4];
#pragma unroll
    for (int i = 0; i < 4; ++i)
      a[i] = *(const half8*)&As[(wm * 64 + i * 16 + l16) * 32 + quad * 8];
#pragma unroll
    for (int j = 0; j < 4; ++j)
      b[j] = *(const half8*)&Bs[(wn * 64 + j * 16 + l16) * 32 + quad * 8];
#pragma unroll
    for (int i = 0; i < 4; ++i)
#pragma unroll
      for (int j = 0; j < 4; ++j)
        acc[i][j] = __builtin_amdgcn_mfma_f32_16x16x32_f16(a[i], b[j], acc[i][j], 0, 0, 0);
  }

  const int rb = m0 + wm * 64 + quad * 4;
  const int cb = n0 + wn * 64 + l16;
#pragma unroll
  for (int j = 0; j < 4; ++j) {
    const float bj = bias[cb + j * 16];
#pragma unroll
    for (int i = 0; i < 4; ++i) {
#pragma unroll
      for (int r = 0; r < 4; ++r) {
        float v = acc[i][j][r] + bj;
        size_t idx = (size_t)(rb + i * 16 + r) * N + cb + j * 16;
        if constexpr (OUT_F16) C[idx] = (_Float16)v; else C[idx] = v;
      }
    }
  }
}

// ---------------------------------------------------------------------------
// Postprocess: RMSNorm(q,k over INNER) + weights + rotary + history scale.
// q pre-scaled by 0.125*log2(e) (softmax in log2 domain).
// ---------------------------------------------------------------------------
__global__ __launch_bounds__(256)
void postprocess(const _Float16* __restrict__ qkvh, const float* __restrict__ rot,
                 const float* __restrict__ nqw, const float* __restrict__ nkw,
                 const float* __restrict__ hks, const int* __restrict__ octx,
                 _Float16* __restrict__ qo_, _Float16* __restrict__ ko_) {
  const int token = blockIdx.x;
  const int b = token >> 11, spos = token & (S - 1);
  const int tid = threadIdx.x;
  const _Float16* qrow = qkvh + (size_t)token * QKVN;
  const _Float16* krow = qrow + INNER;
  const float* r = rot + (size_t)token * (2 * HD);

  const int e0 = tid * 4;
  half4v qs = *(const half4v*)(qrow + e0);
  half4v ks = *(const half4v*)(krow + e0);
  float q4[4], k4[4];
#pragma unroll
  for (int i = 0; i < 4; ++i) { q4[i] = (float)qs[i]; k4[i] = (float)ks[i]; }

  float sq = 0.f, sk = 0.f;
#pragma unroll
  for (int i = 0; i < 4; ++i) { sq += q4[i] * q4[i]; sk += k4[i] * k4[i]; }
#pragma unroll
  for (int msk = 1; msk < 64; msk <<= 1) {
    sq += __shfl_xor(sq, msk);
    sk += __shfl_xor(sk, msk);
  }
  __shared__ float red[8];
  const int wv = tid >> 6;
  if ((tid & 63) == 0) { red[wv] = sq; red[4 + wv] = sk; }
  __syncthreads();
  sq = red[0] + red[1] + red[2] + red[3];
  sk = red[4] + red[5] + red[6] + red[7];

  const float qinv = 1.0f / sqrtf(sq * (1.0f / INNER) + EPS);
  const float kinv = 1.0f / sqrtf(sk * (1.0f / INNER) + EPS);

#pragma unroll
  for (int i = 0; i < 4; ++i) {
    q4[i] = q4[i] * qinv * nqw[e0 + i];
    k4[i] = k4[i] * kinv * nkw[e0 + i];
  }

  const int h = e0 >> 6, d0 = e0 & (HD - 1);
  const float c0 = r[d0],     s0 = r[HD + d0 + 1];
  const float c1 = r[d0 + 2], s1 = r[HD + d0 + 3];

  float qo[4], ko[4];
  qo[0] = q4[0] * c0 - q4[1] * s0;
  qo[1] = q4[0] * s0 + q4[1] * c0;
  qo[2] = q4[2] * c1 - q4[3] * s1;
  qo[3] = q4[2] * s1 + q4[3] * c1;
  ko[0] = k4[0] * c0 - k4[1] * s0;
  ko[1] = k4[0] * s0 + k4[1] * c0;
  ko[2] = k4[2] * c1 - k4[3] * s1;
  ko[3] = k4[2] * s1 + k4[3] * c1;

  const int hist = S - octx[0];
  if (hist > 0 && spos < hist) {
    const float sig = 1.0f / (1.0f + expf(-hks[h]));
    const float sc = 1.0f + sig * (MAX_SCALE - 1.0f);
#pragma unroll
    for (int i = 0; i < 4; ++i) ko[i] *= sc;
  }

  half4v qo4, ko4;
#pragma unroll
  for (int i = 0; i < 4; ++i) {
    qo4[i] = (_Float16)(qo[i] * SCALE_LOG2E);
    ko4[i] = (_Float16)ko[i];
  }
  const size_t obase = ((size_t)(b * NH + h) * S + spos) * HD + d0;
  *(half4v*)(qo_ + obase) = qo4;
  *(half4v*)(ko_ + obase) = ko4;
}

// ---------------------------------------------------------------------------
// V slice of qkvh -> vT fp16 swizzled for x16 B-frags:
// vt[bh][kt][d][pos], pos(s_local = jj*16+quad*4+i) = quad*16 + jj*4 + i.
// ---------------------------------------------------------------------------
__global__ __launch_bounds__(256)
void prep_vT(const _Float16* __restrict__ qkvh, _Float16* __restrict__ vt) {
  __shared__ _Float16 T[64 * 72];
  const int bh = blockIdx.x;
  const int b = bh >> 4, h = bh & 15;
  const int kt = blockIdx.y;
  const int s0 = kt * 64;
  const int tid = threadIdx.x;
#pragma unroll
  for (int i = 0; i < 2; ++i) {
    int id = tid + 256 * i;
    int s = id >> 3, c = id & 7;
    *(half8*)&T[s * 72 + c * 8] =
        *(const half8*)&qkvh[(size_t)(b * S + s0 + s) * QKVN + 2 * INNER + h * HD + c * 8];
  }
  __syncthreads();
  _Float16* orow = vt + ((size_t)bh * 32 + kt) * 64 * 64;
#pragma unroll
  for (int i = 0; i < 4; ++i) {
    int id = tid + 256 * i;
    int d = id >> 4, g = id & 15;
    int quad = g >> 2, jj = g & 3;
    half4v o;
#pragma unroll
    for (int k = 0; k < 4; ++k) o[k] = T[(jj * 16 + quad * 4 + k) * 72 + d];
    *(half4v*)&orow[d * 64 + g * 4] = o;
  }
}

// ---------------------------------------------------------------------------
// MFMA flash attention, S^T formulation, split-K over 2 partitions
// (blockIdx.z): each partition covers 16 K-tiles and emits normalized O
// (f16) plus per-row (m, l) for the merge kernel.
// ---------------------------------------------------------------------------
__global__ __launch_bounds__(256)
void attn_mfma(const _Float16* __restrict__ qb, const _Float16* __restrict__ kb,
               const _Float16* __restrict__ vt, _Float16* __restrict__ On,
               float2* __restrict__ ml) {
  __shared__ _Float16 Ks[64 * 72];   // [kcol][d]
  __shared__ _Float16 Vs[64 * 72];   // [d][pos] swizzled
  const int bh = blockIdx.x;
  const int q0 = blockIdx.y * 64;
  const int part = blockIdx.z;
  const int tid = threadIdx.x;
  const int wave = tid >> 6, lane = tid & 63, quad = lane >> 4, l16 = lane & 15;

  const _Float16* qbh = qb + (size_t)bh * S * HD;
  const _Float16* kbh = kb + (size_t)bh * S * HD;
  const _Float16* vbh = vt + (size_t)bh * S * HD;

  half8 aq[2];
#pragma unroll
  for (int ks = 0; ks < 2; ++ks)
    aq[ks] = *(const half8*)&qbh[(size_t)(q0 + wave * 16 + l16) * HD + ks * 32 + quad * 8];

  floatx4 o16[4] = {};
  float mrow = -INFINITY, lrow = 0.f;

  for (int kt = part * 16; kt < part * 16 + 16; ++kt) {
    __syncthreads();
#pragma unroll
    for (int i = 0; i < 2; ++i) {
      int id = tid + 256 * i;
      int rr = id >> 3, c = id & 7;
      *(half8*)&Ks[rr * 72 + c * 8] = *(const half8*)&kbh[(size_t)(kt * 64 + rr) * HD + c * 8];
      *(half8*)&Vs[rr * 72 + c * 8] = *(const half8*)&vbh[((size_t)kt * 64 + rr) * 64 + c * 8];
    }
    __syncthreads();

    // S^T = K @ Q^T : sc[jj][r] = S[qrow=l16][kcol = jj*16+quad*4+r]
    floatx4 sc[4] = {};
#pragma unroll
    for (int jj = 0; jj < 4; ++jj) {
#pragma unroll
      for (int ks = 0; ks < 2; ++ks) {
        half8 ak = *(const half8*)&Ks[(jj * 16 + l16) * 72 + ks * 32 + quad * 8];
        sc[jj] = __builtin_amdgcn_mfma_f32_16x16x32_f16(ak, aq[ks], sc[jj], 0, 0, 0);
      }
    }

    // online softmax, one Q-row per lane (log2 domain)
    float mx = -INFINITY;
#pragma unroll
    for (int jj = 0; jj < 4; ++jj)
#pragma unroll
      for (int r = 0; r < 4; ++r) mx = fmaxf(mx, sc[jj][r]);
    mx = fmaxf(mx, __shfl_xor(mx, 16));
    mx = fmaxf(mx, __shfl_xor(mx, 32));
    const float mn = fmaxf(mrow, mx);
    const float alpha = exp2f(mrow - mn);
    mrow = mn;

    float rs = 0.f;
    half4v ap[4];
#pragma unroll
    for (int jj = 0; jj < 4; ++jj) {
#pragma unroll
      for (int r = 0; r < 4; ++r) {
        float p = exp2f(sc[jj][r] - mn);
        rs += p;
        ap[jj][r] = (_Float16)p;
      }
    }
    rs += __shfl_xor(rs, 16);
    rs += __shfl_xor(rs, 32);
    lrow = lrow * alpha + rs;

    // rescale O (O rows at qrow=quad*4+r; alpha lives at qrow=l16)
    float alr[4];
#pragma unroll
    for (int r = 0; r < 4; ++r) alr[r] = __shfl(alpha, quad * 4 + r);
#pragma unroll
    for (int jb = 0; jb < 4; ++jb)
#pragma unroll
      for (int r = 0; r < 4; ++r) o16[jb][r] *= alr[r];

    // O += P @ V : 16x16x16 MFMAs, P direct from registers.
#pragma unroll
    for (int jb = 0; jb < 4; ++jb) {
      half8 v01 = *(const half8*)&Vs[(jb * 16 + l16) * 72 + quad * 16];
      half8 v23 = *(const half8*)&Vs[(jb * 16 + l16) * 72 + quad * 16 + 8];
      half4v b0 = __builtin_shufflevector(v01, v01, 0, 1, 2, 3);
      half4v b1 = __builtin_shufflevector(v01, v01, 4, 5, 6, 7);
      half4v b2 = __builtin_shufflevector(v23, v23, 0, 1, 2, 3);
      half4v b3 = __builtin_shufflevector(v23, v23, 4, 5, 6, 7);
      o16[jb] = MFMA16(ap[0], b0, o16[jb]);
      o16[jb] = MFMA16(ap[1], b1, o16[jb]);
      o16[jb] = MFMA16(ap[2], b2, o16[jb]);
      o16[jb] = MFMA16(ap[3], b3, o16[jb]);
    }
  }

  // epilogue: normalized partial O + (m,l) per row
  float linv[4];
#pragma unroll
  for (int r = 0; r < 4; ++r) linv[r] = 1.0f / __shfl(lrow, quad * 4 + r);
  const size_t pb = (size_t)(part * 32 + bh) * S;
#pragma unroll
  for (int jb = 0; jb < 4; ++jb) {
#pragma unroll
    for (int r = 0; r < 4; ++r) {
      const int row = q0 + wave * 16 + quad * 4 + r;
      On[(pb + row) * HD + jb * 16 + l16] = (_Float16)(o16[jb][r] * linv[r]);
    }
  }
  if (quad == 0)
    ml[pb + q0 + wave * 16 + l16] = make_float2(mrow, lrow);
}

// ---------------------------------------------------------------------------
// Merge 2 split-K partitions: O = (w1*O1n + w2*O2n)/(w1+w2),
// w_i = exp2(m_i - m*) * l_i. Writes attnb in [b*S+s][h*64+d] layout.
// ---------------------------------------------------------------------------
__global__ __launch_bounds__(256)
void attn_merge(const _Float16* __restrict__ On, const float2* __restrict__ ml,
                _Float16* __restrict__ attnb) {
  const int id = blockIdx.x * 256 + threadIdx.x;   // 524288 total
  const int d8 = id & 7;
  const int h  = (id >> 3) & 15;
  const int s  = (id >> 7) & 2047;
  const int b  = id >> 18;
  const int bh = b * 16 + h;
  const float2 m1 = ml[(size_t)bh * S + s];
  const float2 m2 = ml[(size_t)(32 + bh) * S + s];
  const float mm = fmaxf(m1.x, m2.x);
  float w1 = exp2f(m1.x - mm) * m1.y;
  float w2 = exp2f(m2.x - mm) * m2.y;
  const float inv = 1.0f / (w1 + w2);
  w1 *= inv; w2 *= inv;
  const half8 o1 = *(const half8*)&On[((size_t)bh * S + s) * HD + d8 * 8];
  const half8 o2 = *(const half8*)&On[((size_t)(32 + bh) * S + s) * HD + d8 * 8];
  half8 o;
#pragma unroll
  for (int j = 0; j < 8; ++j)
    o[j] = (_Float16)(w1 * (float)o1[j] + w2 * (float)o2[j]);
  *(half8*)&attnb[((size_t)(b * S + s)) * INNER + h * HD + d8 * 8] = o;
}

// ---------------------------------------------------------------------------
extern "C" void kernel_launch(void* const* d_in, const int* in_sizes, int n_in,
                              void* d_out, int out_size, void* d_ws, size_t ws_size,
                              hipStream_t stream) {
  const float* hs    = (const float*)d_in[0];
  const float* rot   = (const float*)d_in[1];
  const float* w_qkv = (const float*)d_in[2];
  const float* b_qkv = (const float*)d_in[3];
  const float* nqw   = (const float*)d_in[4];
  const float* nkw   = (const float*)d_in[5];
  const float* w_out = (const float*)d_in[6];
  const float* b_out = (const float*)d_in[7];
  const float* hks   = (const float*)d_in[8];
  const int*   octx  = (const int*)d_in[9];

  _Float16* hsb   = (_Float16*)d_ws;                 // 0-8 MiB (attnb aliases)
  _Float16* attnb = hsb;
  _Float16* wqkvT = hsb   + (size_t)NTOK * DIM;      // 8-14 MiB
  _Float16* woutT = wqkvT + (size_t)QKVN * DIM;      // 14-16 MiB
  _Float16* qkvh  = woutT + (size_t)DIM * INNER;     // 16-40 MiB
  _Float16* q_h   = qkvh  + (size_t)NTOK * QKVN;     // 40-48 MiB
  _Float16* k_h   = q_h   + (size_t)B * NH * S * HD; // 48-56 MiB
  _Float16* vT    = k_h   + (size_t)B * NH * S * HD; // 56-64 MiB
  // split-K partials alias qkvh (dead after prep_vT): On 16 MiB + ml 1 MiB
  _Float16* On    = qkvh;
  float2*   ml    = (float2*)(qkvh + (size_t)2 * B * NH * S * HD);

  cvt_f16<<<(NTOK * DIM / 8 + 255) / 256, 256, 0, stream>>>(hs, hsb, NTOK * DIM / 8);
  transpose_w<<<dim3(QKVN / 64, DIM / 64), 256, 0, stream>>>(w_qkv, wqkvT, DIM, QKVN);
  transpose_w<<<dim3(DIM / 64, INNER / 64), 256, 0, stream>>>(w_out, woutT, INNER, DIM);

  gemm_bt<true, _Float16><<<dim3(QKVN / 128, NTOK / 128), 256, 0, stream>>>(
      hsb, wqkvT, b_qkv, qkvh, QKVN, DIM);

  postprocess<<<NTOK, 256, 0, stream>>>(qkvh, rot, nqw, nkw, hks, octx, q_h, k_h);
  prep_vT<<<dim3(B * NH, S / 64), 256, 0, stream>>>(qkvh, vT);

  attn_mfma<<<dim3(B * NH, S / 64, 2), 256, 0, stream>>>(q_h, k_h, vT, On, ml);
  attn_merge<<<(B * S * NH * 8) / 256, 256, 0, stream>>>(On, ml, attnb);

  gemm_bt<false, float><<<dim3(DIM / 128, NTOK / 128), 256, 0, stream>>>(
      attnb, woutT, b_out, (float*)d_out, DIM, INNER);
}

// Round 8
// 256.910 us; speedup vs baseline: 1.0422x; 1.0422x over previous
//
#include <hip/hip_runtime.h>
#include <math.h>

typedef float    floatx4 __attribute__((ext_vector_type(4)));
typedef _Float16 half8   __attribute__((ext_vector_type(8)));
typedef _Float16 half4v  __attribute__((ext_vector_type(4)));

constexpr int B    = 2;
constexpr int S    = 2048;
constexpr int NH   = 16;
constexpr int HD   = 64;
constexpr int DIM  = 1024;
constexpr int INNER = 1024;
constexpr int QKVN = 3072;
constexpr int NTOK = 4096;
constexpr float EPS = 1e-5f;
constexpr float MAX_SCALE = 10.0f;
constexpr float SCALE_LOG2E = 0.125f * 1.4426950408889634f;

#define MFMA16(a, b, c) __builtin_amdgcn_mfma_f32_16x16x16f16((a), (b), (c), 0, 0, 0)

// ---------------------------------------------------------------------------
// fp32 -> fp16 elementwise convert (8 elems/thread)
// ---------------------------------------------------------------------------
__global__ __launch_bounds__(256)
void cvt_f16(const float* __restrict__ in, _Float16* __restrict__ out, int n8) {
  int id = blockIdx.x * 256 + threadIdx.x;
  if (id >= n8) return;
  const float4 a = ((const float4*)in)[id * 2];
  const float4 b = ((const float4*)in)[id * 2 + 1];
  half8 o;
  o[0] = (_Float16)a.x; o[1] = (_Float16)a.y; o[2] = (_Float16)a.z; o[3] = (_Float16)a.w;
  o[4] = (_Float16)b.x; o[5] = (_Float16)b.y; o[6] = (_Float16)b.z; o[7] = (_Float16)b.w;
  ((half8*)out)[id] = o;
}

// ---------------------------------------------------------------------------
// w [K][N] fp32  ->  wT [N][K] fp16   (64x64 tiles through LDS)
// ---------------------------------------------------------------------------
__global__ __launch_bounds__(256)
void transpose_w(const float* __restrict__ w, _Float16* __restrict__ wT, int K, int N) {
  __shared__ _Float16 T[64 * 72];
  const int k0 = blockIdx.y * 64, n0 = blockIdx.x * 64;
  const int tid = threadIdx.x;
#pragma unroll
  for (int i = 0; i < 4; ++i) {
    int id = tid + 256 * i;
    int r = id >> 4, c = id & 15;
    float4 v = *(const float4*)&w[(size_t)(k0 + r) * N + n0 + c * 4];
    half4v s; s[0] = (_Float16)v.x; s[1] = (_Float16)v.y;
    s[2] = (_Float16)v.z; s[3] = (_Float16)v.w;
    *(half4v*)&T[r * 72 + c * 4] = s;
  }
  __syncthreads();
#pragma unroll
  for (int i = 0; i < 2; ++i) {
    int id = tid + 256 * i;
    int n = id >> 3, cs = id & 7;
    half8 o;
#pragma unroll
    for (int jj = 0; jj < 8; ++jj) o[jj] = T[(cs * 8 + jj) * 72 + n];
    *(half8*)&wT[(size_t)(n0 + n) * K + k0 + cs * 8] = o;
  }
}

// ---------------------------------------------------------------------------
// fp16 MFMA GEMM (R5 structure): C[M][N] = A[M][K] @ BT[N][K]^T + bias
// 128x128 tile, 256 thr (4 waves, 2x2), BK=32, 16x16x32 MFMA, 4x4 acc/wave.
// LDS rows padded to 56 halves (112 B: 16B-aligned, 2-way banks = free).
// ---------------------------------------------------------------------------
template<bool OUT_F16, typename OutT>
__global__ __launch_bounds__(256)
void gemm_bt(const _Float16* __restrict__ A, const _Float16* __restrict__ BT,
             const float* __restrict__ bias, OutT* __restrict__ C, int N, int K) {
  __shared__ _Float16 As[128 * 56];
  __shared__ _Float16 Bs[128 * 56];
  const int tid = threadIdx.x;
  const int wave = tid >> 6, lane = tid & 63, quad = lane >> 4, l16 = lane & 15;
  const int wm = wave >> 1, wn = wave & 1;
  const int m0 = blockIdx.y * 128, n0 = blockIdx.x * 128;

  floatx4 acc[4][4] = {};

  for (int k0 = 0; k0 < K; k0 += 32) {
    __syncthreads();
#pragma unroll
    for (int i = 0; i < 2; ++i) {
      int id = tid + 256 * i;
      int m = id >> 2, c = id & 3;
      *(half8*)&As[m * 56 + c * 8] = *(const half8*)&A[(size_t)(m0 + m) * K + k0 + c * 8];
      *(half8*)&Bs[m * 56 + c * 8] = *(const half8*)&BT[(size_t)(n0 + m) * K + k0 + c * 8];
    }
    __syncthreads();
    half8 a[4], b[4];
#pragma unroll
    for (int i = 0; i < 4; ++i)
      a[i] = *(const half8*)&As[(wm * 64 + i * 16 + l16) * 56 + quad * 8];
#pragma unroll
    for (int j = 0; j < 4; ++j)
      b[j] = *(const half8*)&Bs[(wn * 64 + j * 16 + l16) * 56 + quad * 8];
#pragma unroll
    for (int i = 0; i < 4; ++i)
#pragma unroll
      for (int j = 0; j < 4; ++j)
        acc[i][j] = __builtin_amdgcn_mfma_f32_16x16x32_f16(a[i], b[j], acc[i][j], 0, 0, 0);
  }

  const int rb = m0 + wm * 64 + quad * 4;
  const int cb = n0 + wn * 64 + l16;
#pragma unroll
  for (int j = 0; j < 4; ++j) {
    const float bj = bias[cb + j * 16];
#pragma unroll
    for (int i = 0; i < 4; ++i) {
#pragma unroll
      for (int r = 0; r < 4; ++r) {
        float v = acc[i][j][r] + bj;
        size_t idx = (size_t)(rb + i * 16 + r) * N + cb + j * 16;
        if constexpr (OUT_F16) C[idx] = (_Float16)v; else C[idx] = v;
      }
    }
  }
}

// ---------------------------------------------------------------------------
// Postprocess: RMSNorm(q,k over INNER) + weights + rotary + history scale.
// q pre-scaled by 0.125*log2(e) (softmax in log2 domain).
// ---------------------------------------------------------------------------
__global__ __launch_bounds__(256)
void postprocess(const _Float16* __restrict__ qkvh, const float* __restrict__ rot,
                 const float* __restrict__ nqw, const float* __restrict__ nkw,
                 const float* __restrict__ hks, const int* __restrict__ octx,
                 _Float16* __restrict__ qo_, _Float16* __restrict__ ko_) {
  const int token = blockIdx.x;
  const int b = token >> 11, spos = token & (S - 1);
  const int tid = threadIdx.x;
  const _Float16* qrow = qkvh + (size_t)token * QKVN;
  const _Float16* krow = qrow + INNER;
  const float* r = rot + (size_t)token * (2 * HD);

  const int e0 = tid * 4;
  half4v qs = *(const half4v*)(qrow + e0);
  half4v ks = *(const half4v*)(krow + e0);
  float q4[4], k4[4];
#pragma unroll
  for (int i = 0; i < 4; ++i) { q4[i] = (float)qs[i]; k4[i] = (float)ks[i]; }

  float sq = 0.f, sk = 0.f;
#pragma unroll
  for (int i = 0; i < 4; ++i) { sq += q4[i] * q4[i]; sk += k4[i] * k4[i]; }
#pragma unroll
  for (int msk = 1; msk < 64; msk <<= 1) {
    sq += __shfl_xor(sq, msk);
    sk += __shfl_xor(sk, msk);
  }
  __shared__ float red[8];
  const int wv = tid >> 6;
  if ((tid & 63) == 0) { red[wv] = sq; red[4 + wv] = sk; }
  __syncthreads();
  sq = red[0] + red[1] + red[2] + red[3];
  sk = red[4] + red[5] + red[6] + red[7];

  const float qinv = 1.0f / sqrtf(sq * (1.0f / INNER) + EPS);
  const float kinv = 1.0f / sqrtf(sk * (1.0f / INNER) + EPS);

#pragma unroll
  for (int i = 0; i < 4; ++i) {
    q4[i] = q4[i] * qinv * nqw[e0 + i];
    k4[i] = k4[i] * kinv * nkw[e0 + i];
  }

  const int h = e0 >> 6, d0 = e0 & (HD - 1);
  const float c0 = r[d0],     s0 = r[HD + d0 + 1];
  const float c1 = r[d0 + 2], s1 = r[HD + d0 + 3];

  float qo[4], ko[4];
  qo[0] = q4[0] * c0 - q4[1] * s0;
  qo[1] = q4[0] * s0 + q4[1] * c0;
  qo[2] = q4[2] * c1 - q4[3] * s1;
  qo[3] = q4[2] * s1 + q4[3] * c1;
  ko[0] = k4[0] * c0 - k4[1] * s0;
  ko[1] = k4[0] * s0 + k4[1] * c0;
  ko[2] = k4[2] * c1 - k4[3] * s1;
  ko[3] = k4[2] * s1 + k4[3] * c1;

  const int hist = S - octx[0];
  if (hist > 0 && spos < hist) {
    const float sig = 1.0f / (1.0f + expf(-hks[h]));
    const float sc = 1.0f + sig * (MAX_SCALE - 1.0f);
#pragma unroll
    for (int i = 0; i < 4; ++i) ko[i] *= sc;
  }

  half4v qo4, ko4;
#pragma unroll
  for (int i = 0; i < 4; ++i) {
    qo4[i] = (_Float16)(qo[i] * SCALE_LOG2E);
    ko4[i] = (_Float16)ko[i];
  }
  const size_t obase = ((size_t)(b * NH + h) * S + spos) * HD + d0;
  *(half4v*)(qo_ + obase) = qo4;
  *(half4v*)(ko_ + obase) = ko4;
}

// ---------------------------------------------------------------------------
// V slice of qkvh -> vT fp16 swizzled for x16 B-frags:
// vt[bh][kt][d][pos], pos(s_local = jj*16+quad*4+i) = quad*16 + jj*4 + i.
// ---------------------------------------------------------------------------
__global__ __launch_bounds__(256)
void prep_vT(const _Float16* __restrict__ qkvh, _Float16* __restrict__ vt) {
  __shared__ _Float16 T[64 * 72];
  const int bh = blockIdx.x;
  const int b = bh >> 4, h = bh & 15;
  const int kt = blockIdx.y;
  const int s0 = kt * 64;
  const int tid = threadIdx.x;
#pragma unroll
  for (int i = 0; i < 2; ++i) {
    int id = tid + 256 * i;
    int s = id >> 3, c = id & 7;
    *(half8*)&T[s * 72 + c * 8] =
        *(const half8*)&qkvh[(size_t)(b * S + s0 + s) * QKVN + 2 * INNER + h * HD + c * 8];
  }
  __syncthreads();
  _Float16* orow = vt + ((size_t)bh * 32 + kt) * 64 * 64;
#pragma unroll
  for (int i = 0; i < 4; ++i) {
    int id = tid + 256 * i;
    int d = id >> 4, g = id & 15;
    int quad = g >> 2, jj = g & 3;
    half4v o;
#pragma unroll
    for (int k = 0; k < 4; ++k) o[k] = T[(jj * 16 + quad * 4 + k) * 72 + d];
    *(half4v*)&orow[d * 64 + g * 4] = o;
  }
}

// ---------------------------------------------------------------------------
// MFMA flash attention, S^T formulation, IN-BLOCK split-K.
// 512 thr = 8 waves: waves 0-3 = K-partition 0 (tiles 0..15),
// waves 4-7 = partition 1 (tiles 16..31). Each wave owns 16 Q rows.
// Staging is register-pipelined: next tile's global loads issue after the
// ds_write, hiding load latency under the current tile's compute.
// Final merge of the two partitions through LDS (reused tile memory).
// ---------------------------------------------------------------------------
__global__ __launch_bounds__(512)
void attn_mfma(const _Float16* __restrict__ qb, const _Float16* __restrict__ kb,
               const _Float16* __restrict__ vt, _Float16* __restrict__ attnb) {
  __shared__ __align__(16) char smem[36864];   // 2 partitions x (Ks 9216 + Vs 9216)
  const int bh = blockIdx.x;
  const int b = bh >> 4, h = bh & 15;
  const int q0 = blockIdx.y * 64;
  const int tid = threadIdx.x;
  const int wave = tid >> 6, lane = tid & 63, quad = lane >> 4, l16 = lane & 15;
  const int part = wave >> 2, wq = wave & 3;

  _Float16* Kp = (_Float16*)(smem + part * 18432);
  _Float16* Vp = (_Float16*)(smem + part * 18432 + 9216);

  const _Float16* qbh = qb + (size_t)bh * S * HD;
  const _Float16* kbh = kb + (size_t)bh * S * HD;
  const _Float16* vbh = vt + (size_t)bh * S * HD;

  // Q fragments (B-operand of the S^T MFMA)
  half8 aq[2];
#pragma unroll
  for (int ks = 0; ks < 2; ++ks)
    aq[ks] = *(const half8*)&qbh[(size_t)(q0 + wq * 16 + l16) * HD + ks * 32 + quad * 8];

  // staging indices: 256 threads per partition, 2 chunks each per matrix
  const int st = (wq << 6) | lane;          // 0..255 within partition
  int rr[2], cc[2];
#pragma unroll
  for (int i = 0; i < 2; ++i) { int id = st + 256 * i; rr[i] = id >> 3; cc[i] = (id & 7) * 8; }

  const int kt0 = part * 16;
  half8 kreg[2], vreg[2];
#pragma unroll
  for (int i = 0; i < 2; ++i) {
    kreg[i] = *(const half8*)&kbh[(size_t)(kt0 * 64 + rr[i]) * HD + cc[i]];
    vreg[i] = *(const half8*)&vbh[((size_t)kt0 * 64 + rr[i]) * 64 + cc[i]];
  }

  floatx4 o16[4] = {};
  float mrow = -INFINITY, lrow = 0.f;

  for (int t = 0; t < 16; ++t) {
    __syncthreads();
#pragma unroll
    for (int i = 0; i < 2; ++i) {
      *(half8*)&Kp[rr[i] * 72 + cc[i]] = kreg[i];
      *(half8*)&Vp[rr[i] * 72 + cc[i]] = vreg[i];
    }
    if (t < 15) {
      const int ktn = kt0 + t + 1;
#pragma unroll
      for (int i = 0; i < 2; ++i) {
        kreg[i] = *(const half8*)&kbh[(size_t)(ktn * 64 + rr[i]) * HD + cc[i]];
        vreg[i] = *(const half8*)&vbh[((size_t)ktn * 64 + rr[i]) * 64 + cc[i]];
      }
    }
    __syncthreads();

    // S^T = K @ Q^T : sc[jj][r] = S[qrow=l16][kcol = jj*16+quad*4+r]
    floatx4 sc[4] = {};
#pragma unroll
    for (int jj = 0; jj < 4; ++jj) {
#pragma unroll
      for (int ks = 0; ks < 2; ++ks) {
        half8 ak = *(const half8*)&Kp[(jj * 16 + l16) * 72 + ks * 32 + quad * 8];
        sc[jj] = __builtin_amdgcn_mfma_f32_16x16x32_f16(ak, aq[ks], sc[jj], 0, 0, 0);
      }
    }

    // online softmax, one Q-row per lane (log2 domain)
    float mx = -INFINITY;
#pragma unroll
    for (int jj = 0; jj < 4; ++jj)
#pragma unroll
      for (int r = 0; r < 4; ++r) mx = fmaxf(mx, sc[jj][r]);
    mx = fmaxf(mx, __shfl_xor(mx, 16));
    mx = fmaxf(mx, __shfl_xor(mx, 32));
    const float mn = fmaxf(mrow, mx);
    const float alpha = exp2f(mrow - mn);
    mrow = mn;

    float rs = 0.f;
    half4v ap[4];
#pragma unroll
    for (int jj = 0; jj < 4; ++jj) {
#pragma unroll
      for (int r = 0; r < 4; ++r) {
        float p = exp2f(sc[jj][r] - mn);
        rs += p;
        ap[jj][r] = (_Float16)p;
      }
    }
    rs += __shfl_xor(rs, 16);
    rs += __shfl_xor(rs, 32);
    lrow = lrow * alpha + rs;

    // rescale O (O rows at qrow=quad*4+r; alpha lives at qrow=l16)
    float alr[4];
#pragma unroll
    for (int r = 0; r < 4; ++r) alr[r] = __shfl(alpha, quad * 4 + r);
#pragma unroll
    for (int jb = 0; jb < 4; ++jb)
#pragma unroll
      for (int r = 0; r < 4; ++r) o16[jb][r] *= alr[r];

    // O += P @ V : 16x16x16 MFMAs, P direct from registers.
#pragma unroll
    for (int jb = 0; jb < 4; ++jb) {
      half8 v01 = *(const half8*)&Vp[(jb * 16 + l16) * 72 + quad * 16];
      half8 v23 = *(const half8*)&Vp[(jb * 16 + l16) * 72 + quad * 16 + 8];
      half4v b0 = __builtin_shufflevector(v01, v01, 0, 1, 2, 3);
      half4v b1 = __builtin_shufflevector(v01, v01, 4, 5, 6, 7);
      half4v b2 = __builtin_shufflevector(v23, v23, 0, 1, 2, 3);
      half4v b3 = __builtin_shufflevector(v23, v23, 4, 5, 6, 7);
      o16[jb] = MFMA16(ap[0], b0, o16[jb]);
      o16[jb] = MFMA16(ap[1], b1, o16[jb]);
      o16[jb] = MFMA16(ap[2], b2, o16[jb]);
      o16[jb] = MFMA16(ap[3], b3, o16[jb]);
    }
  }

  // ---- merge the two partitions through LDS (reuse tile memory) ----
  float*  Os  = (float*)smem;                 // [4 wq][16 row][65] f32
  float2* ml1 = (float2*)(smem + 16640);      // [64]
  __syncthreads();
  if (part == 1) {
#pragma unroll
    for (int jb = 0; jb < 4; ++jb)
#pragma unroll
      for (int r = 0; r < 4; ++r)
        Os[(wq * 16 + quad * 4 + r) * 65 + jb * 16 + l16] = o16[jb][r];
    if (quad == 0) ml1[wq * 16 + l16] = make_float2(mrow, lrow);
  }
  __syncthreads();
  if (part == 0) {
    const float2 m1v = ml1[wq * 16 + l16];
    const float mm = fmaxf(mrow, m1v.x);
    const float w0 = exp2f(mrow - mm), w1 = exp2f(m1v.x - mm);
    const float inv = 1.0f / (w0 * lrow + w1 * m1v.y);
    const float u0 = w0 * inv, u1 = w1 * inv;
    float u0r[4], u1r[4];
#pragma unroll
    for (int r = 0; r < 4; ++r) {
      u0r[r] = __shfl(u0, quad * 4 + r);
      u1r[r] = __shfl(u1, quad * 4 + r);
    }
#pragma unroll
    for (int jb = 0; jb < 4; ++jb) {
#pragma unroll
      for (int r = 0; r < 4; ++r) {
        const float o1 = Os[(wq * 16 + quad * 4 + r) * 65 + jb * 16 + l16];
        const float v = u0r[r] * o16[jb][r] + u1r[r] * o1;
        const int row = q0 + wq * 16 + quad * 4 + r;
        attnb[(size_t)(b * S + row) * INNER + h * HD + jb * 16 + l16] = (_Float16)v;
      }
    }
  }
}

// ---------------------------------------------------------------------------
extern "C" void kernel_launch(void* const* d_in, const int* in_sizes, int n_in,
                              void* d_out, int out_size, void* d_ws, size_t ws_size,
                              hipStream_t stream) {
  const float* hs    = (const float*)d_in[0];
  const float* rot   = (const float*)d_in[1];
  const float* w_qkv = (const float*)d_in[2];
  const float* b_qkv = (const float*)d_in[3];
  const float* nqw   = (const float*)d_in[4];
  const float* nkw   = (const float*)d_in[5];
  const float* w_out = (const float*)d_in[6];
  const float* b_out = (const float*)d_in[7];
  const float* hks   = (const float*)d_in[8];
  const int*   octx  = (const int*)d_in[9];

  _Float16* hsb   = (_Float16*)d_ws;                 // 0-8 MiB (attnb aliases)
  _Float16* attnb = hsb;
  _Float16* wqkvT = hsb   + (size_t)NTOK * DIM;      // 8-14 MiB
  _Float16* woutT = wqkvT + (size_t)QKVN * DIM;      // 14-16 MiB
  _Float16* qkvh  = woutT + (size_t)DIM * INNER;     // 16-40 MiB
  _Float16* q_h   = qkvh  + (size_t)NTOK * QKVN;     // 40-48 MiB
  _Float16* k_h   = q_h   + (size_t)B * NH * S * HD; // 48-56 MiB
  _Float16* vT    = k_h   + (size_t)B * NH * S * HD; // 56-64 MiB

  cvt_f16<<<(NTOK * DIM / 8 + 255) / 256, 256, 0, stream>>>(hs, hsb, NTOK * DIM / 8);
  transpose_w<<<dim3(QKVN / 64, DIM / 64), 256, 0, stream>>>(w_qkv, wqkvT, DIM, QKVN);
  transpose_w<<<dim3(DIM / 64, INNER / 64), 256, 0, stream>>>(w_out, woutT, INNER, DIM);

  gemm_bt<true, _Float16><<<dim3(QKVN / 128, NTOK / 128), 256, 0, stream>>>(
      hsb, wqkvT, b_qkv, qkvh, QKVN, DIM);

  postprocess<<<NTOK, 256, 0, stream>>>(qkvh, rot, nqw, nkw, hks, octx, q_h, k_h);
  prep_vT<<<dim3(B * NH, S / 64), 256, 0, stream>>>(qkvh, vT);

  attn_mfma<<<dim3(B * NH, S / 64), 512, 0, stream>>>(q_h, k_h, vT, attnb);

  gemm_bt<false, float><<<dim3(DIM / 128, NTOK / 128), 256, 0, stream>>>(
      attnb, woutT, b_out, (float*)d_out, DIM, INNER);
}

// Round 9
// 234.086 us; speedup vs baseline: 1.1438x; 1.0975x over previous
//
#include <hip/hip_runtime.h>
#include <math.h>

typedef float    floatx4 __attribute__((ext_vector_type(4)));
typedef _Float16 half8   __attribute__((ext_vector_type(8)));
typedef _Float16 half4v  __attribute__((ext_vector_type(4)));

constexpr int B    = 2;
constexpr int S    = 2048;
constexpr int NH   = 16;
constexpr int HD   = 64;
constexpr int DIM  = 1024;
constexpr int INNER = 1024;
constexpr int QKVN = 3072;
constexpr int NTOK = 4096;
constexpr float EPS = 1e-5f;
constexpr float MAX_SCALE = 10.0f;
constexpr float SCALE_LOG2E = 0.125f * 1.4426950408889634f;

#define MFMA16(a, b, c) __builtin_amdgcn_mfma_f32_16x16x16f16((a), (b), (c), 0, 0, 0)

// ---------------------------------------------------------------------------
// Fused prep: blockIdx [0,2048) fp32->fp16 convert of hs;
// [2048,2816) transpose w_qkv; [2816,3072) transpose w_out.
// ---------------------------------------------------------------------------
__device__ __forceinline__ void transpose_tile(const float* __restrict__ w,
                                               _Float16* __restrict__ wT,
                                               int K, int N, int k0, int n0,
                                               _Float16* T, int tid) {
#pragma unroll
  for (int i = 0; i < 4; ++i) {
    int id = tid + 256 * i;
    int r = id >> 4, c = id & 15;
    float4 v = *(const float4*)&w[(size_t)(k0 + r) * N + n0 + c * 4];
    half4v s; s[0] = (_Float16)v.x; s[1] = (_Float16)v.y;
    s[2] = (_Float16)v.z; s[3] = (_Float16)v.w;
    *(half4v*)&T[r * 72 + c * 4] = s;
  }
  __syncthreads();
#pragma unroll
  for (int i = 0; i < 2; ++i) {
    int id = tid + 256 * i;
    int n = id >> 3, cs = id & 7;
    half8 o;
#pragma unroll
    for (int jj = 0; jj < 8; ++jj) o[jj] = T[(cs * 8 + jj) * 72 + n];
    *(half8*)&wT[(size_t)(n0 + n) * K + k0 + cs * 8] = o;
  }
}

__global__ __launch_bounds__(256)
void prep_all(const float* __restrict__ hs, const float* __restrict__ w_qkv,
              const float* __restrict__ w_out, _Float16* __restrict__ hsb,
              _Float16* __restrict__ wqkvT, _Float16* __restrict__ woutT) {
  __shared__ _Float16 T[64 * 72];
  const int bx = blockIdx.x, tid = threadIdx.x;
  if (bx < 2048) {            // cvt: 2048*256 == NTOK*DIM/8 exactly
    int id = bx * 256 + tid;
    const float4 a = ((const float4*)hs)[id * 2];
    const float4 b = ((const float4*)hs)[id * 2 + 1];
    half8 o;
    o[0] = (_Float16)a.x; o[1] = (_Float16)a.y; o[2] = (_Float16)a.z; o[3] = (_Float16)a.w;
    o[4] = (_Float16)b.x; o[5] = (_Float16)b.y; o[6] = (_Float16)b.z; o[7] = (_Float16)b.w;
    ((half8*)hsb)[id] = o;
  } else if (bx < 2816) {     // w_qkv: 48 n-tiles x 16 k-tiles
    int id = bx - 2048;
    transpose_tile(w_qkv, wqkvT, DIM, QKVN, (id / 48) * 64, (id % 48) * 64, T, tid);
  } else {                    // w_out: 16 x 16
    int id = bx - 2816;
    transpose_tile(w_out, woutT, INNER, DIM, (id / 16) * 64, (id % 16) * 64, T, tid);
  }
}

// ---------------------------------------------------------------------------
// fp16 MFMA GEMM with register-prefetch staging (loads for tile t+1 issued
// before compute(t); global latency hides under compute).
// ---------------------------------------------------------------------------
template<bool OUT_F16, typename OutT>
__global__ __launch_bounds__(256)
void gemm_bt(const _Float16* __restrict__ A, const _Float16* __restrict__ BT,
             const float* __restrict__ bias, OutT* __restrict__ C, int N, int K) {
  __shared__ _Float16 As[128 * 56];
  __shared__ _Float16 Bs[128 * 56];
  const int tid = threadIdx.x;
  const int wave = tid >> 6, lane = tid & 63, quad = lane >> 4, l16 = lane & 15;
  const int wm = wave >> 1, wn = wave & 1;
  const int m0 = blockIdx.y * 128, n0 = blockIdx.x * 128;

  const int id0 = tid, id1 = tid + 256;
  const int m_0 = id0 >> 2, c_0 = (id0 & 3) * 8;
  const int m_1 = id1 >> 2, c_1 = (id1 & 3) * 8;
  const _Float16* Ap0 = A + (size_t)(m0 + m_0) * K + c_0;
  const _Float16* Ap1 = A + (size_t)(m0 + m_1) * K + c_1;
  const _Float16* Bp0 = BT + (size_t)(n0 + m_0) * K + c_0;
  const _Float16* Bp1 = BT + (size_t)(n0 + m_1) * K + c_1;

  half8 ar0 = *(const half8*)Ap0, ar1 = *(const half8*)Ap1;
  half8 br0 = *(const half8*)Bp0, br1 = *(const half8*)Bp1;

  floatx4 acc[4][4] = {};

  for (int k0 = 0; k0 < K; k0 += 32) {
    __syncthreads();
    *(half8*)&As[m_0 * 56 + c_0] = ar0;
    *(half8*)&As[m_1 * 56 + c_1] = ar1;
    *(half8*)&Bs[m_0 * 56 + c_0] = br0;
    *(half8*)&Bs[m_1 * 56 + c_1] = br1;
    if (k0 + 32 < K) {
      ar0 = *(const half8*)(Ap0 + k0 + 32);
      ar1 = *(const half8*)(Ap1 + k0 + 32);
      br0 = *(const half8*)(Bp0 + k0 + 32);
      br1 = *(const half8*)(Bp1 + k0 + 32);
    }
    __syncthreads();
    half8 a[4], b[4];
#pragma unroll
    for (int i = 0; i < 4; ++i)
      a[i] = *(const half8*)&As[(wm * 64 + i * 16 + l16) * 56 + quad * 8];
#pragma unroll
    for (int j = 0; j < 4; ++j)
      b[j] = *(const half8*)&Bs[(wn * 64 + j * 16 + l16) * 56 + quad * 8];
#pragma unroll
    for (int i = 0; i < 4; ++i)
#pragma unroll
      for (int j = 0; j < 4; ++j)
        acc[i][j] = __builtin_amdgcn_mfma_f32_16x16x32_f16(a[i], b[j], acc[i][j], 0, 0, 0);
  }

  const int rb = m0 + wm * 64 + quad * 4;
  const int cb = n0 + wn * 64 + l16;
#pragma unroll
  for (int j = 0; j < 4; ++j) {
    const float bj = bias[cb + j * 16];
#pragma unroll
    for (int i = 0; i < 4; ++i) {
#pragma unroll
      for (int r = 0; r < 4; ++r) {
        float v = acc[i][j][r] + bj;
        size_t idx = (size_t)(rb + i * 16 + r) * N + cb + j * 16;
        if constexpr (OUT_F16) C[idx] = (_Float16)v; else C[idx] = v;
      }
    }
  }
}

// ---------------------------------------------------------------------------
// Fused post: blockIdx [0,4096) = per-token RMSNorm+rotary+hist-scale;
// [4096,5120) = V transpose/swizzle tiles.
// ---------------------------------------------------------------------------
__global__ __launch_bounds__(256)
void post_all(const _Float16* __restrict__ qkvh, const float* __restrict__ rot,
              const float* __restrict__ nqw, const float* __restrict__ nkw,
              const float* __restrict__ hks, const int* __restrict__ octx,
              _Float16* __restrict__ qo_, _Float16* __restrict__ ko_,
              _Float16* __restrict__ vt) {
  __shared__ __align__(16) char arena[64 * 72 * 2];
  const int tid = threadIdx.x;
  if (blockIdx.x < 4096) {
    float* red = (float*)arena;
    const int token = blockIdx.x;
    const int b = token >> 11, spos = token & (S - 1);
    const _Float16* qrow = qkvh + (size_t)token * QKVN;
    const _Float16* krow = qrow + INNER;
    const float* r = rot + (size_t)token * (2 * HD);

    const int e0 = tid * 4;
    half4v qs = *(const half4v*)(qrow + e0);
    half4v ks = *(const half4v*)(krow + e0);
    float q4[4], k4[4];
#pragma unroll
    for (int i = 0; i < 4; ++i) { q4[i] = (float)qs[i]; k4[i] = (float)ks[i]; }

    float sq = 0.f, sk = 0.f;
#pragma unroll
    for (int i = 0; i < 4; ++i) { sq += q4[i] * q4[i]; sk += k4[i] * k4[i]; }
#pragma unroll
    for (int msk = 1; msk < 64; msk <<= 1) {
      sq += __shfl_xor(sq, msk);
      sk += __shfl_xor(sk, msk);
    }
    const int wv = tid >> 6;
    if ((tid & 63) == 0) { red[wv] = sq; red[4 + wv] = sk; }
    __syncthreads();
    sq = red[0] + red[1] + red[2] + red[3];
    sk = red[4] + red[5] + red[6] + red[7];

    const float qinv = 1.0f / sqrtf(sq * (1.0f / INNER) + EPS);
    const float kinv = 1.0f / sqrtf(sk * (1.0f / INNER) + EPS);

#pragma unroll
    for (int i = 0; i < 4; ++i) {
      q4[i] = q4[i] * qinv * nqw[e0 + i];
      k4[i] = k4[i] * kinv * nkw[e0 + i];
    }

    const int h = e0 >> 6, d0 = e0 & (HD - 1);
    const float c0 = r[d0],     s0 = r[HD + d0 + 1];
    const float c1 = r[d0 + 2], s1 = r[HD + d0 + 3];

    float qo[4], ko[4];
    qo[0] = q4[0] * c0 - q4[1] * s0;
    qo[1] = q4[0] * s0 + q4[1] * c0;
    qo[2] = q4[2] * c1 - q4[3] * s1;
    qo[3] = q4[2] * s1 + q4[3] * c1;
    ko[0] = k4[0] * c0 - k4[1] * s0;
    ko[1] = k4[0] * s0 + k4[1] * c0;
    ko[2] = k4[2] * c1 - k4[3] * s1;
    ko[3] = k4[2] * s1 + k4[3] * c1;

    const int hist = S - octx[0];
    if (hist > 0 && spos < hist) {
      const float sig = 1.0f / (1.0f + expf(-hks[h]));
      const float sc = 1.0f + sig * (MAX_SCALE - 1.0f);
#pragma unroll
      for (int i = 0; i < 4; ++i) ko[i] *= sc;
    }

    half4v qo4, ko4;
#pragma unroll
    for (int i = 0; i < 4; ++i) {
      qo4[i] = (_Float16)(qo[i] * SCALE_LOG2E);
      ko4[i] = (_Float16)ko[i];
    }
    const size_t obase = ((size_t)(b * NH + h) * S + spos) * HD + d0;
    *(half4v*)(qo_ + obase) = qo4;
    *(half4v*)(ko_ + obase) = ko4;
  } else {
    _Float16* T = (_Float16*)arena;
    const int id = blockIdx.x - 4096;
    const int bh = id & 31, kt = id >> 5;
    const int b = bh >> 4, h = bh & 15;
    const int s0 = kt * 64;
#pragma unroll
    for (int i = 0; i < 2; ++i) {
      int id2 = tid + 256 * i;
      int s = id2 >> 3, c = id2 & 7;
      *(half8*)&T[s * 72 + c * 8] =
          *(const half8*)&qkvh[(size_t)(b * S + s0 + s) * QKVN + 2 * INNER + h * HD + c * 8];
    }
    __syncthreads();
    _Float16* orow = vt + ((size_t)bh * 32 + kt) * 64 * 64;
#pragma unroll
    for (int i = 0; i < 4; ++i) {
      int id2 = tid + 256 * i;
      int d = id2 >> 4, g = id2 & 15;
      int quad = g >> 2, jj = g & 3;
      half4v o;
#pragma unroll
      for (int k = 0; k < 4; ++k) o[k] = T[(jj * 16 + quad * 4 + k) * 72 + d];
      *(half4v*)&orow[d * 64 + g * 4] = o;
    }
  }
}

// ---------------------------------------------------------------------------
// MFMA flash attention: 512 thr = 8 waves cover a 128-row Q tile (16 rows
// per wave), no split-K. K/V tiles double-buffered in LDS (one barrier per
// tile) with register prefetch one tile ahead.
// ---------------------------------------------------------------------------
__global__ __launch_bounds__(512)
void attn_mfma(const _Float16* __restrict__ qb, const _Float16* __restrict__ kb,
               const _Float16* __restrict__ vt, _Float16* __restrict__ attnb) {
  __shared__ _Float16 Kb0[64 * 72], Vb0[64 * 72];
  __shared__ _Float16 Kb1[64 * 72], Vb1[64 * 72];
  const int bh = blockIdx.x;
  const int b = bh >> 4, h = bh & 15;
  const int q0 = blockIdx.y * 128;
  const int tid = threadIdx.x;
  const int wave = tid >> 6, lane = tid & 63, quad = lane >> 4, l16 = lane & 15;

  const _Float16* qbh = qb + (size_t)bh * S * HD;
  const _Float16* kbh = kb + (size_t)bh * S * HD;
  const _Float16* vbh = vt + (size_t)bh * S * HD;

  // Q fragments (B-operand of the S^T MFMA)
  half8 aq[2];
#pragma unroll
  for (int ks = 0; ks < 2; ++ks)
    aq[ks] = *(const half8*)&qbh[(size_t)(q0 + wave * 16 + l16) * HD + ks * 32 + quad * 8];

  // staging: 512 threads, one half8 chunk each for K and V per tile
  const int rr = tid >> 3, cc = (tid & 7) * 8;
  const _Float16* kptr = kbh + (size_t)rr * HD + cc;
  const _Float16* vptr = vbh + (size_t)rr * 64 + cc;

  half8 kreg = *(const half8*)kptr, vreg = *(const half8*)vptr;   // tile 0
  *(half8*)&Kb0[rr * 72 + cc] = kreg;
  *(half8*)&Vb0[rr * 72 + cc] = vreg;
  kptr += 64 * HD; vptr += 64 * 64;
  kreg = *(const half8*)kptr; vreg = *(const half8*)vptr;         // tile 1
  __syncthreads();

  floatx4 o16[4] = {};
  float mrow = -INFINITY, lrow = 0.f;

  auto compute = [&](const _Float16* Kp, const _Float16* Vp) {
    // S^T = K @ Q^T : sc[jj][r] = S[qrow=l16][kcol = jj*16+quad*4+r]
    floatx4 sc[4] = {};
#pragma unroll
    for (int jj = 0; jj < 4; ++jj) {
#pragma unroll
      for (int ks = 0; ks < 2; ++ks) {
        half8 ak = *(const half8*)&Kp[(jj * 16 + l16) * 72 + ks * 32 + quad * 8];
        sc[jj] = __builtin_amdgcn_mfma_f32_16x16x32_f16(ak, aq[ks], sc[jj], 0, 0, 0);
      }
    }

    // online softmax, one Q-row per lane (log2 domain)
    float mx = -INFINITY;
#pragma unroll
    for (int jj = 0; jj < 4; ++jj)
#pragma unroll
      for (int r = 0; r < 4; ++r) mx = fmaxf(mx, sc[jj][r]);
    mx = fmaxf(mx, __shfl_xor(mx, 16));
    mx = fmaxf(mx, __shfl_xor(mx, 32));
    const float mn = fmaxf(mrow, mx);
    const float alpha = exp2f(mrow - mn);
    mrow = mn;

    float rs = 0.f;
    half4v ap[4];
#pragma unroll
    for (int jj = 0; jj < 4; ++jj) {
#pragma unroll
      for (int r = 0; r < 4; ++r) {
        float p = exp2f(sc[jj][r] - mn);
        rs += p;
        ap[jj][r] = (_Float16)p;
      }
    }
    rs += __shfl_xor(rs, 16);
    rs += __shfl_xor(rs, 32);
    lrow = lrow * alpha + rs;

    // rescale O (O rows at qrow=quad*4+r; alpha lives at qrow=l16)
    float alr[4];
#pragma unroll
    for (int r = 0; r < 4; ++r) alr[r] = __shfl(alpha, quad * 4 + r);
#pragma unroll
    for (int jb = 0; jb < 4; ++jb)
#pragma unroll
      for (int r = 0; r < 4; ++r) o16[jb][r] *= alr[r];

    // O += P @ V : 16x16x16 MFMAs, P direct from registers.
#pragma unroll
    for (int jb = 0; jb < 4; ++jb) {
      half8 v01 = *(const half8*)&Vp[(jb * 16 + l16) * 72 + quad * 16];
      half8 v23 = *(const half8*)&Vp[(jb * 16 + l16) * 72 + quad * 16 + 8];
      half4v b0 = __builtin_shufflevector(v01, v01, 0, 1, 2, 3);
      half4v b1 = __builtin_shufflevector(v01, v01, 4, 5, 6, 7);
      half4v b2 = __builtin_shufflevector(v23, v23, 0, 1, 2, 3);
      half4v b3 = __builtin_shufflevector(v23, v23, 4, 5, 6, 7);
      o16[jb] = MFMA16(ap[0], b0, o16[jb]);
      o16[jb] = MFMA16(ap[1], b1, o16[jb]);
      o16[jb] = MFMA16(ap[2], b2, o16[jb]);
      o16[jb] = MFMA16(ap[3], b3, o16[jb]);
    }
  };

  for (int t = 0; t < 32; t += 2) {
    // even iter: regs hold tile t+1 -> buf1; compute buf0 (tile t)
    *(half8*)&Kb1[rr * 72 + cc] = kreg;
    *(half8*)&Vb1[rr * 72 + cc] = vreg;
    if (t + 2 < 32) {
      kptr += 64 * HD; vptr += 64 * 64;
      kreg = *(const half8*)kptr; vreg = *(const half8*)vptr;
    }
    compute(Kb0, Vb0);
    __syncthreads();
    // odd iter: regs hold tile t+2 -> buf0; compute buf1 (tile t+1)
    if (t + 2 < 32) {
      *(half8*)&Kb0[rr * 72 + cc] = kreg;
      *(half8*)&Vb0[rr * 72 + cc] = vreg;
      if (t + 3 < 32) {
        kptr += 64 * HD; vptr += 64 * 64;
        kreg = *(const half8*)kptr; vreg = *(const half8*)vptr;
      }
    }
    compute(Kb1, Vb1);
    __syncthreads();
  }

  // epilogue: divide by l (broadcast to O layout) and store
  float linv[4];
#pragma unroll
  for (int r = 0; r < 4; ++r) linv[r] = 1.0f / __shfl(lrow, quad * 4 + r);
#pragma unroll
  for (int jb = 0; jb < 4; ++jb) {
#pragma unroll
    for (int r = 0; r < 4; ++r) {
      const int row = q0 + wave * 16 + quad * 4 + r;
      attnb[(size_t)(b * S + row) * INNER + h * HD + jb * 16 + l16] =
          (_Float16)(o16[jb][r] * linv[r]);
    }
  }
}

// ---------------------------------------------------------------------------
extern "C" void kernel_launch(void* const* d_in, const int* in_sizes, int n_in,
                              void* d_out, int out_size, void* d_ws, size_t ws_size,
                              hipStream_t stream) {
  const float* hs    = (const float*)d_in[0];
  const float* rot   = (const float*)d_in[1];
  const float* w_qkv = (const float*)d_in[2];
  const float* b_qkv = (const float*)d_in[3];
  const float* nqw   = (const float*)d_in[4];
  const float* nkw   = (const float*)d_in[5];
  const float* w_out = (const float*)d_in[6];
  const float* b_out = (const float*)d_in[7];
  const float* hks   = (const float*)d_in[8];
  const int*   octx  = (const int*)d_in[9];

  _Float16* hsb   = (_Float16*)d_ws;                 // 0-8 MiB (attnb aliases)
  _Float16* attnb = hsb;
  _Float16* wqkvT = hsb   + (size_t)NTOK * DIM;      // 8-14 MiB
  _Float16* woutT = wqkvT + (size_t)QKVN * DIM;      // 14-16 MiB
  _Float16* qkvh  = woutT + (size_t)DIM * INNER;     // 16-40 MiB
  _Float16* q_h   = qkvh  + (size_t)NTOK * QKVN;     // 40-48 MiB
  _Float16* k_h   = q_h   + (size_t)B * NH * S * HD; // 48-56 MiB
  _Float16* vT    = k_h   + (size_t)B * NH * S * HD; // 56-64 MiB

  prep_all<<<3072, 256, 0, stream>>>(hs, w_qkv, w_out, hsb, wqkvT, woutT);

  gemm_bt<true, _Float16><<<dim3(QKVN / 128, NTOK / 128), 256, 0, stream>>>(
      hsb, wqkvT, b_qkv, qkvh, QKVN, DIM);

  post_all<<<5120, 256, 0, stream>>>(qkvh, rot, nqw, nkw, hks, octx, q_h, k_h, vT);

  attn_mfma<<<dim3(B * NH, S / 128), 512, 0, stream>>>(q_h, k_h, vT, attnb);

  gemm_bt<false, float><<<dim3(DIM / 128, NTOK / 128), 256, 0, stream>>>(
      attnb, woutT, b_out, (float*)d_out, DIM, INNER);
}

// Round 10
// 220.234 us; speedup vs baseline: 1.2157x; 1.0629x over previous
//
#include <hip/hip_runtime.h>
#include <math.h>

typedef float    floatx4 __attribute__((ext_vector_type(4)));
typedef _Float16 half8   __attribute__((ext_vector_type(8)));
typedef _Float16 half4v  __attribute__((ext_vector_type(4)));
typedef _Float16 half2v  __attribute__((ext_vector_type(2)));
typedef __fp16   fp16x2  __attribute__((ext_vector_type(2)));

constexpr int B    = 2;
constexpr int S    = 2048;
constexpr int NH   = 16;
constexpr int HD   = 64;
constexpr int DIM  = 1024;
constexpr int INNER = 1024;
constexpr int QKVN = 3072;
constexpr int NTOK = 4096;
constexpr float EPS = 1e-5f;
constexpr float MAX_SCALE = 10.0f;
constexpr float SCALE_LOG2E = 0.125f * 1.4426950408889634f;

#define MFMA16(a, b, c) __builtin_amdgcn_mfma_f32_16x16x16f16((a), (b), (c), 0, 0, 0)

__device__ __forceinline__ half2v pkrtz(float a, float b) {
  fp16x2 t = __builtin_amdgcn_cvt_pkrtz(a, b);
  return __builtin_bit_cast(half2v, t);
}
__device__ __forceinline__ half2v hmax2(half2v a, half2v b) {
  return __builtin_elementwise_max(a, b);
}

// ---------------------------------------------------------------------------
// Fused prep: blockIdx [0,2048) fp32->fp16 convert of hs;
// [2048,2816) transpose w_qkv; [2816,3072) transpose w_out.
// ---------------------------------------------------------------------------
__device__ __forceinline__ void transpose_tile(const float* __restrict__ w,
                                               _Float16* __restrict__ wT,
                                               int K, int N, int k0, int n0,
                                               _Float16* T, int tid) {
#pragma unroll
  for (int i = 0; i < 4; ++i) {
    int id = tid + 256 * i;
    int r = id >> 4, c = id & 15;
    float4 v = *(const float4*)&w[(size_t)(k0 + r) * N + n0 + c * 4];
    half4v s; s[0] = (_Float16)v.x; s[1] = (_Float16)v.y;
    s[2] = (_Float16)v.z; s[3] = (_Float16)v.w;
    *(half4v*)&T[r * 72 + c * 4] = s;
  }
  __syncthreads();
#pragma unroll
  for (int i = 0; i < 2; ++i) {
    int id = tid + 256 * i;
    int n = id >> 3, cs = id & 7;
    half8 o;
#pragma unroll
    for (int jj = 0; jj < 8; ++jj) o[jj] = T[(cs * 8 + jj) * 72 + n];
    *(half8*)&wT[(size_t)(n0 + n) * K + k0 + cs * 8] = o;
  }
}

__global__ __launch_bounds__(256)
void prep_all(const float* __restrict__ hs, const float* __restrict__ w_qkv,
              const float* __restrict__ w_out, _Float16* __restrict__ hsb,
              _Float16* __restrict__ wqkvT, _Float16* __restrict__ woutT) {
  __shared__ _Float16 T[64 * 72];
  const int bx = blockIdx.x, tid = threadIdx.x;
  if (bx < 2048) {
    int id = bx * 256 + tid;
    const float4 a = ((const float4*)hs)[id * 2];
    const float4 b = ((const float4*)hs)[id * 2 + 1];
    half8 o;
    o[0] = (_Float16)a.x; o[1] = (_Float16)a.y; o[2] = (_Float16)a.z; o[3] = (_Float16)a.w;
    o[4] = (_Float16)b.x; o[5] = (_Float16)b.y; o[6] = (_Float16)b.z; o[7] = (_Float16)b.w;
    ((half8*)hsb)[id] = o;
  } else if (bx < 2816) {
    int id = bx - 2048;
    transpose_tile(w_qkv, wqkvT, DIM, QKVN, (id / 48) * 64, (id % 48) * 64, T, tid);
  } else {
    int id = bx - 2816;
    transpose_tile(w_out, woutT, INNER, DIM, (id / 16) * 64, (id % 16) * 64, T, tid);
  }
}

// ---------------------------------------------------------------------------
// fp16 MFMA GEMM with register-prefetch staging (unchanged from R9).
// ---------------------------------------------------------------------------
template<bool OUT_F16, typename OutT>
__global__ __launch_bounds__(256)
void gemm_bt(const _Float16* __restrict__ A, const _Float16* __restrict__ BT,
             const float* __restrict__ bias, OutT* __restrict__ C, int N, int K) {
  __shared__ _Float16 As[128 * 56];
  __shared__ _Float16 Bs[128 * 56];
  const int tid = threadIdx.x;
  const int wave = tid >> 6, lane = tid & 63, quad = lane >> 4, l16 = lane & 15;
  const int wm = wave >> 1, wn = wave & 1;
  const int m0 = blockIdx.y * 128, n0 = blockIdx.x * 128;

  const int id0 = tid, id1 = tid + 256;
  const int m_0 = id0 >> 2, c_0 = (id0 & 3) * 8;
  const int m_1 = id1 >> 2, c_1 = (id1 & 3) * 8;
  const _Float16* Ap0 = A + (size_t)(m0 + m_0) * K + c_0;
  const _Float16* Ap1 = A + (size_t)(m0 + m_1) * K + c_1;
  const _Float16* Bp0 = BT + (size_t)(n0 + m_0) * K + c_0;
  const _Float16* Bp1 = BT + (size_t)(n0 + m_1) * K + c_1;

  half8 ar0 = *(const half8*)Ap0, ar1 = *(const half8*)Ap1;
  half8 br0 = *(const half8*)Bp0, br1 = *(const half8*)Bp1;

  floatx4 acc[4][4] = {};

  for (int k0 = 0; k0 < K; k0 += 32) {
    __syncthreads();
    *(half8*)&As[m_0 * 56 + c_0] = ar0;
    *(half8*)&As[m_1 * 56 + c_1] = ar1;
    *(half8*)&Bs[m_0 * 56 + c_0] = br0;
    *(half8*)&Bs[m_1 * 56 + c_1] = br1;
    if (k0 + 32 < K) {
      ar0 = *(const half8*)(Ap0 + k0 + 32);
      ar1 = *(const half8*)(Ap1 + k0 + 32);
      br0 = *(const half8*)(Bp0 + k0 + 32);
      br1 = *(const half8*)(Bp1 + k0 + 32);
    }
    __syncthreads();
    half8 a[4], b[4];
#pragma unroll
    for (int i = 0; i < 4; ++i)
      a[i] = *(const half8*)&As[(wm * 64 + i * 16 + l16) * 56 + quad * 8];
#pragma unroll
    for (int j = 0; j < 4; ++j)
      b[j] = *(const half8*)&Bs[(wn * 64 + j * 16 + l16) * 56 + quad * 8];
#pragma unroll
    for (int i = 0; i < 4; ++i)
#pragma unroll
      for (int j = 0; j < 4; ++j)
        acc[i][j] = __builtin_amdgcn_mfma_f32_16x16x32_f16(a[i], b[j], acc[i][j], 0, 0, 0);
  }

  const int rb = m0 + wm * 64 + quad * 4;
  const int cb = n0 + wn * 64 + l16;
#pragma unroll
  for (int j = 0; j < 4; ++j) {
    const float bj = bias[cb + j * 16];
#pragma unroll
    for (int i = 0; i < 4; ++i) {
#pragma unroll
      for (int r = 0; r < 4; ++r) {
        float v = acc[i][j][r] + bj;
        size_t idx = (size_t)(rb + i * 16 + r) * N + cb + j * 16;
        if constexpr (OUT_F16) C[idx] = (_Float16)v; else C[idx] = v;
      }
    }
  }
}

// ---------------------------------------------------------------------------
// Fused post: blockIdx [0,4096) = per-token RMSNorm+rotary+hist-scale;
// [4096,5120) = V transpose/swizzle tiles.
// ---------------------------------------------------------------------------
__global__ __launch_bounds__(256)
void post_all(const _Float16* __restrict__ qkvh, const float* __restrict__ rot,
              const float* __restrict__ nqw, const float* __restrict__ nkw,
              const float* __restrict__ hks, const int* __restrict__ octx,
              _Float16* __restrict__ qo_, _Float16* __restrict__ ko_,
              _Float16* __restrict__ vt) {
  __shared__ __align__(16) char arena[64 * 72 * 2];
  const int tid = threadIdx.x;
  if (blockIdx.x < 4096) {
    float* red = (float*)arena;
    const int token = blockIdx.x;
    const int b = token >> 11, spos = token & (S - 1);
    const _Float16* qrow = qkvh + (size_t)token * QKVN;
    const _Float16* krow = qrow + INNER;
    const float* r = rot + (size_t)token * (2 * HD);

    const int e0 = tid * 4;
    half4v qs = *(const half4v*)(qrow + e0);
    half4v ks = *(const half4v*)(krow + e0);
    float q4[4], k4[4];
#pragma unroll
    for (int i = 0; i < 4; ++i) { q4[i] = (float)qs[i]; k4[i] = (float)ks[i]; }

    float sq = 0.f, sk = 0.f;
#pragma unroll
    for (int i = 0; i < 4; ++i) { sq += q4[i] * q4[i]; sk += k4[i] * k4[i]; }
#pragma unroll
    for (int msk = 1; msk < 64; msk <<= 1) {
      sq += __shfl_xor(sq, msk);
      sk += __shfl_xor(sk, msk);
    }
    const int wv = tid >> 6;
    if ((tid & 63) == 0) { red[wv] = sq; red[4 + wv] = sk; }
    __syncthreads();
    sq = red[0] + red[1] + red[2] + red[3];
    sk = red[4] + red[5] + red[6] + red[7];

    const float qinv = 1.0f / sqrtf(sq * (1.0f / INNER) + EPS);
    const float kinv = 1.0f / sqrtf(sk * (1.0f / INNER) + EPS);

#pragma unroll
    for (int i = 0; i < 4; ++i) {
      q4[i] = q4[i] * qinv * nqw[e0 + i];
      k4[i] = k4[i] * kinv * nkw[e0 + i];
    }

    const int h = e0 >> 6, d0 = e0 & (HD - 1);
    const float c0 = r[d0],     s0 = r[HD + d0 + 1];
    const float c1 = r[d0 + 2], s1 = r[HD + d0 + 3];

    float qo[4], ko[4];
    qo[0] = q4[0] * c0 - q4[1] * s0;
    qo[1] = q4[0] * s0 + q4[1] * c0;
    qo[2] = q4[2] * c1 - q4[3] * s1;
    qo[3] = q4[2] * s1 + q4[3] * c1;
    ko[0] = k4[0] * c0 - k4[1] * s0;
    ko[1] = k4[0] * s0 + k4[1] * c0;
    ko[2] = k4[2] * c1 - k4[3] * s1;
    ko[3] = k4[2] * s1 + k4[3] * c1;

    const int hist = S - octx[0];
    if (hist > 0 && spos < hist) {
      const float sig = 1.0f / (1.0f + expf(-hks[h]));
      const float sc = 1.0f + sig * (MAX_SCALE - 1.0f);
#pragma unroll
      for (int i = 0; i < 4; ++i) ko[i] *= sc;
    }

    half4v qo4, ko4;
#pragma unroll
    for (int i = 0; i < 4; ++i) {
      qo4[i] = (_Float16)(qo[i] * SCALE_LOG2E);
      ko4[i] = (_Float16)ko[i];
    }
    const size_t obase = ((size_t)(b * NH + h) * S + spos) * HD + d0;
    *(half4v*)(qo_ + obase) = qo4;
    *(half4v*)(ko_ + obase) = ko4;
  } else {
    _Float16* T = (_Float16*)arena;
    const int id = blockIdx.x - 4096;
    const int bh = id & 31, kt = id >> 5;
    const int b = bh >> 4, h = bh & 15;
    const int s0 = kt * 64;
#pragma unroll
    for (int i = 0; i < 2; ++i) {
      int id2 = tid + 256 * i;
      int s = id2 >> 3, c = id2 & 7;
      *(half8*)&T[s * 72 + c * 8] =
          *(const half8*)&qkvh[(size_t)(b * S + s0 + s) * QKVN + 2 * INNER + h * HD + c * 8];
    }
    __syncthreads();
    _Float16* orow = vt + ((size_t)bh * 32 + kt) * 64 * 64;
#pragma unroll
    for (int i = 0; i < 4; ++i) {
      int id2 = tid + 256 * i;
      int d = id2 >> 4, g = id2 & 15;
      int quad = g >> 2, jj = g & 3;
      half4v o;
#pragma unroll
      for (int k = 0; k < 4; ++k) o[k] = T[(jj * 16 + quad * 4 + k) * 72 + d];
      *(half4v*)&orow[d * 64 + g * 4] = o;
    }
  }
}

// ---------------------------------------------------------------------------
// MFMA flash attention: 512 thr = 8 waves cover a 128-row Q tile, double-
// buffered LDS, register prefetch. Softmax in packed f16 (pk_max/pk_sub/
// v_exp_f16/v_dot2) with conditional O-rescale via __ballot.
// ---------------------------------------------------------------------------
__global__ __launch_bounds__(512)
void attn_mfma(const _Float16* __restrict__ qb, const _Float16* __restrict__ kb,
               const _Float16* __restrict__ vt, _Float16* __restrict__ attnb) {
  __shared__ _Float16 Kb0[64 * 72], Vb0[64 * 72];
  __shared__ _Float16 Kb1[64 * 72], Vb1[64 * 72];
  const int bh = blockIdx.x;
  const int b = bh >> 4, h = bh & 15;
  const int q0 = blockIdx.y * 128;
  const int tid = threadIdx.x;
  const int wave = tid >> 6, lane = tid & 63, quad = lane >> 4, l16 = lane & 15;

  const _Float16* qbh = qb + (size_t)bh * S * HD;
  const _Float16* kbh = kb + (size_t)bh * S * HD;
  const _Float16* vbh = vt + (size_t)bh * S * HD;

  half8 aq[2];
#pragma unroll
  for (int ks = 0; ks < 2; ++ks)
    aq[ks] = *(const half8*)&qbh[(size_t)(q0 + wave * 16 + l16) * HD + ks * 32 + quad * 8];

  const int rr = tid >> 3, cc = (tid & 7) * 8;
  const _Float16* kptr = kbh + (size_t)rr * HD + cc;
  const _Float16* vptr = vbh + (size_t)rr * 64 + cc;

  half8 kreg = *(const half8*)kptr, vreg = *(const half8*)vptr;   // tile 0
  *(half8*)&Kb0[rr * 72 + cc] = kreg;
  *(half8*)&Vb0[rr * 72 + cc] = vreg;
  kptr += 64 * HD; vptr += 64 * 64;
  kreg = *(const half8*)kptr; vreg = *(const half8*)vptr;         // tile 1
  __syncthreads();

  floatx4 o16[4] = {};
  float mrow = -INFINITY, lrow = 0.f;

  auto compute = [&](const _Float16* Kp, const _Float16* Vp) {
    // S^T = K @ Q^T : sc[jj][r] = S[qrow=l16][kcol = jj*16+quad*4+r]
    floatx4 sc[4] = {};
#pragma unroll
    for (int jj = 0; jj < 4; ++jj) {
#pragma unroll
      for (int ks = 0; ks < 2; ++ks) {
        half8 ak = *(const half8*)&Kp[(jj * 16 + l16) * 72 + ks * 32 + quad * 8];
        sc[jj] = __builtin_amdgcn_mfma_f32_16x16x32_f16(ak, aq[ks], sc[jj], 0, 0, 0);
      }
    }

    // ---- packed f16 online softmax (log2 domain; scale pre-folded in q) ----
    half2v ph[8];
#pragma unroll
    for (int jj = 0; jj < 4; ++jj) {
      ph[jj * 2]     = pkrtz(sc[jj][0], sc[jj][1]);
      ph[jj * 2 + 1] = pkrtz(sc[jj][2], sc[jj][3]);
    }
    // packed max tree over 16 scores
    half2v m0 = hmax2(hmax2(ph[0], ph[1]), hmax2(ph[2], ph[3]));
    half2v m1 = hmax2(hmax2(ph[4], ph[5]), hmax2(ph[6], ph[7]));
    half2v mx2 = hmax2(m0, m1);
    int mi = __builtin_bit_cast(int, mx2);
    mx2 = hmax2(mx2, __builtin_bit_cast(half2v, __shfl_xor(mi, 16)));
    mi = __builtin_bit_cast(int, mx2);
    mx2 = hmax2(mx2, __builtin_bit_cast(half2v, __shfl_xor(mi, 32)));
    const float mxf = fmaxf((float)mx2[0], (float)mx2[1]);
    const float mn = fmaxf(mrow, mxf);
    const bool up = mn > mrow;
    const float alpha = up ? exp2f(mrow - mn) : 1.0f;
    mrow = mn;

    // packed sub + f16 exp2
    const _Float16 mnh = (_Float16)mn;
    half2v mn2; mn2[0] = mnh; mn2[1] = mnh;
    half2v pe[8];
#pragma unroll
    for (int i = 0; i < 8; ++i)
      pe[i] = __builtin_elementwise_exp2(ph[i] - mn2);

    // row-sum via v_dot2 (f32 accumulate, full precision on l)
    half2v one2; one2[0] = (_Float16)1.f; one2[1] = (_Float16)1.f;
    const fp16x2 one2p = __builtin_bit_cast(fp16x2, one2);
    float rs = 0.f;
#pragma unroll
    for (int i = 0; i < 8; ++i)
      rs = __builtin_amdgcn_fdot2(__builtin_bit_cast(fp16x2, pe[i]), one2p, rs, false);
    rs += __shfl_xor(rs, 16);
    rs += __shfl_xor(rs, 32);
    lrow = lrow * alpha + rs;

    // conditional rescale: only when some lane saw a new max
    if (__ballot(up)) {
      float alr[4];
#pragma unroll
      for (int r = 0; r < 4; ++r) alr[r] = __shfl(alpha, quad * 4 + r);
#pragma unroll
      for (int jb = 0; jb < 4; ++jb)
#pragma unroll
        for (int r = 0; r < 4; ++r) o16[jb][r] *= alr[r];
    }

    // P already f16: assemble A-frags for PV
    half4v ap[4];
#pragma unroll
    for (int jj = 0; jj < 4; ++jj)
      ap[jj] = __builtin_shufflevector(pe[jj * 2], pe[jj * 2 + 1], 0, 1, 2, 3);

    // O += P @ V : 16x16x16 MFMAs, P direct from registers.
#pragma unroll
    for (int jb = 0; jb < 4; ++jb) {
      half8 v01 = *(const half8*)&Vp[(jb * 16 + l16) * 72 + quad * 16];
      half8 v23 = *(const half8*)&Vp[(jb * 16 + l16) * 72 + quad * 16 + 8];
      half4v b0 = __builtin_shufflevector(v01, v01, 0, 1, 2, 3);
      half4v b1 = __builtin_shufflevector(v01, v01, 4, 5, 6, 7);
      half4v b2 = __builtin_shufflevector(v23, v23, 0, 1, 2, 3);
      half4v b3 = __builtin_shufflevector(v23, v23, 4, 5, 6, 7);
      o16[jb] = MFMA16(ap[0], b0, o16[jb]);
      o16[jb] = MFMA16(ap[1], b1, o16[jb]);
      o16[jb] = MFMA16(ap[2], b2, o16[jb]);
      o16[jb] = MFMA16(ap[3], b3, o16[jb]);
    }
  };

  for (int t = 0; t < 32; t += 2) {
    *(half8*)&Kb1[rr * 72 + cc] = kreg;
    *(half8*)&Vb1[rr * 72 + cc] = vreg;
    if (t + 2 < 32) {
      kptr += 64 * HD; vptr += 64 * 64;
      kreg = *(const half8*)kptr; vreg = *(const half8*)vptr;
    }
    compute(Kb0, Vb0);
    __syncthreads();
    if (t + 2 < 32) {
      *(half8*)&Kb0[rr * 72 + cc] = kreg;
      *(half8*)&Vb0[rr * 72 + cc] = vreg;
      if (t + 3 < 32) {
        kptr += 64 * HD; vptr += 64 * 64;
        kreg = *(const half8*)kptr; vreg = *(const half8*)vptr;
      }
    }
    compute(Kb1, Vb1);
    __syncthreads();
  }

  float linv[4];
#pragma unroll
  for (int r = 0; r < 4; ++r) linv[r] = 1.0f / __shfl(lrow, quad * 4 + r);
#pragma unroll
  for (int jb = 0; jb < 4; ++jb) {
#pragma unroll
    for (int r = 0; r < 4; ++r) {
      const int row = q0 + wave * 16 + quad * 4 + r;
      attnb[(size_t)(b * S + row) * INNER + h * HD + jb * 16 + l16] =
          (_Float16)(o16[jb][r] * linv[r]);
    }
  }
}

// ---------------------------------------------------------------------------
extern "C" void kernel_launch(void* const* d_in, const int* in_sizes, int n_in,
                              void* d_out, int out_size, void* d_ws, size_t ws_size,
                              hipStream_t stream) {
  const float* hs    = (const float*)d_in[0];
  const float* rot   = (const float*)d_in[1];
  const float* w_qkv = (const float*)d_in[2];
  const float* b_qkv = (const float*)d_in[3];
  const float* nqw   = (const float*)d_in[4];
  const float* nkw   = (const float*)d_in[5];
  const float* w_out = (const float*)d_in[6];
  const float* b_out = (const float*)d_in[7];
  const float* hks   = (const float*)d_in[8];
  const int*   octx  = (const int*)d_in[9];

  _Float16* hsb   = (_Float16*)d_ws;                 // 0-8 MiB (attnb aliases)
  _Float16* attnb = hsb;
  _Float16* wqkvT = hsb   + (size_t)NTOK * DIM;      // 8-14 MiB
  _Float16* woutT = wqkvT + (size_t)QKVN * DIM;      // 14-16 MiB
  _Float16* qkvh  = woutT + (size_t)DIM * INNER;     // 16-40 MiB
  _Float16* q_h   = qkvh  + (size_t)NTOK * QKVN;     // 40-48 MiB
  _Float16* k_h   = q_h   + (size_t)B * NH * S * HD; // 48-56 MiB
  _Float16* vT    = k_h   + (size_t)B * NH * S * HD; // 56-64 MiB

  prep_all<<<3072, 256, 0, stream>>>(hs, w_qkv, w_out, hsb, wqkvT, woutT);

  gemm_bt<true, _Float16><<<dim3(QKVN / 128, NTOK / 128), 256, 0, stream>>>(
      hsb, wqkvT, b_qkv, qkvh, QKVN, DIM);

  post_all<<<5120, 256, 0, stream>>>(qkvh, rot, nqw, nkw, hks, octx, q_h, k_h, vT);

  attn_mfma<<<dim3(B * NH, S / 128), 512, 0, stream>>>(q_h, k_h, vT, attnb);

  gemm_bt<false, float><<<dim3(DIM / 128, NTOK / 128), 256, 0, stream>>>(
      attnb, woutT, b_out, (float*)d_out, DIM, INNER);
}